// Round 4
// baseline (361.860 us; speedup 1.0000x reference)
//
#include <hip/hip_runtime.h>

#define N_PMT 180
#define N_CLUSTERS 128
#define NBINS 2048           // sort bins: vox >> 7  (128-voxel slabs)
#define SPB 8                // slabs per MM block (2048 / 256)
#define GBLK 256             // MM blocks (1 per CU)
#define GT 1024              // MM threads per block (16 waves, 4x4 grid)
#define SORT_T 1024
#define SORT_CAP 8192        // max points per cluster held in LDS (64 KB)
#define BLOCK 256
#define NWAVE (BLOCK / 64)

typedef short bf16x8 __attribute__((ext_vector_type(8)));
typedef float f32x4  __attribute__((ext_vector_type(4)));

static __device__ __forceinline__ unsigned short f2bf(float f) {
    unsigned u = __float_as_uint(f);
    u += 0x7FFFu + ((u >> 16) & 1u);            // round-to-nearest-even
    return (unsigned short)(u >> 16);
}

// swizzled dword index for bf16 matrix [row][128 k]: 16B chunk XOR'd by row&7
// (T2: spreads both the transpose-write and the b128 fragment-read across banks)
static __device__ __forceinline__ int swz_dw(int row, int v) {
    return row * 64 + ((((v >> 3) ^ (row & 7)) << 2)) + ((v >> 1) & 3);
}

// ---- workspace layout (bytes) ----
// 0       : int   offsC[N_CLUSTERS+1]
// 1024    : float dxc[N_CLUSTERS]                  (fallback path only)
// 2048    : int   bucketOffs[128][NBINS+1]         (1,049,088 B)
// +BO     : uint2 sorted[n]                        (vox, q_bits) slab-sorted per cluster
// +8n     : float partial[GBLK][128][180]          (23,592,960 B, if ws permits)

// ---------------- fused voxelize + 2048-bin counting sort, 1 block/cluster ---
__global__ __launch_bounds__(SORT_T) void k_voxsort(
    const float4* __restrict__ batch,
    const float*  __restrict__ dx,
    const int*    __restrict__ sizes,
    const float*  __restrict__ dx_ranges,
    int*          __restrict__ offsC,
    int*          __restrict__ bucketOffs,
    uint2*        __restrict__ sorted) {

    __shared__ uint2 svq[SORT_CAP];            // 64 KB
    __shared__ int hist[NBINS];                // 8 KB
    __shared__ int cur[NBINS];                 // 8 KB
    __shared__ int tsA[SORT_T], tsB[SORT_T];   // 8 KB
    __shared__ int sSz[N_CLUSTERS];
    __shared__ int sE0;

    const int c = blockIdx.x, t = threadIdx.x;
    if (t < N_CLUSTERS) sSz[t] = sizes[t];
    hist[2*t] = 0; hist[2*t+1] = 0;
    __syncthreads();
    if (t == 0) {
        int acc = 0;
        for (int i = 0; i < c; ++i) acc += sSz[i];
        sE0 = acc;
        offsC[c] = acc;
        if (c == N_CLUSTERS - 1) offsC[N_CLUSTERS] = acc + sSz[c];
    }
    __syncthreads();
    const int e0 = sE0, cnt = sSz[c];
    const float lo = dx_ranges[2*c], hi = dx_ranges[2*c+1];
    const float dxcc = fminf(fmaxf(dx[c], lo), hi);
    const bool fits = (cnt <= SORT_CAP);       // wave-uniform

    for (int i = t; i < cnt; i += SORT_T) {
        float4 pd = batch[e0 + i];
        int ix = max(0, min(63, (int)floorf(pd.x + dxcc)));
        int iy = max(0, min(63, (int)floorf(pd.y)));
        int iz = max(0, min(63, (int)floorf(pd.z)));
        unsigned vox = (unsigned)(ix + 64 * (iy + 64 * iz));
        if (fits) svq[i] = make_uint2(vox, __float_as_uint(pd.w));
        atomicAdd(&hist[vox >> 7], 1);
    }
    __syncthreads();
    // scan: thread t owns bins 2t, 2t+1
    const int h0 = hist[2*t], h1 = hist[2*t+1];
    const int tsum = h0 + h1;
    tsA[t] = tsum;
    __syncthreads();
    int* src = tsA; int* dst = tsB;
    for (int d = 1; d < SORT_T; d <<= 1) {     // Hillis-Steele inclusive over 1024
        dst[t] = src[t] + (t >= d ? src[t - d] : 0);
        __syncthreads();
        int* tmp = src; src = dst; dst = tmp;
    }
    const int texcl = src[t] - tsum;           // exclusive prefix of this thread's pair
    cur[2*t]   = texcl;
    cur[2*t+1] = texcl + h0;
    {
        int* bo = bucketOffs + (size_t)c * (NBINS + 1);
        bo[2*t]   = e0 + texcl;
        bo[2*t+1] = e0 + texcl + h0;
        if (t == SORT_T - 1) bo[NBINS] = e0 + cnt;
    }
    __syncthreads();
    if (fits) {
        for (int i = t; i < cnt; i += SORT_T) {
            uint2 e = svq[i];
            int pos = atomicAdd(&cur[e.x >> 7], 1);
            sorted[e0 + pos] = e;
        }
    } else {                                   // general-size: re-read batch
        for (int i = t; i < cnt; i += SORT_T) {
            float4 pd = batch[e0 + i];
            int ix = max(0, min(63, (int)floorf(pd.x + dxcc)));
            int iy = max(0, min(63, (int)floorf(pd.y)));
            int iz = max(0, min(63, (int)floorf(pd.z)));
            unsigned vox = (unsigned)(ix + 64 * (iy + 64 * iz));
            int pos = atomicAdd(&cur[vox >> 7], 1);
            sorted[e0 + pos] = make_uint2(vox, __float_as_uint(pd.w));
        }
    }
}

// ---------------- per-slab dense-W MFMA: out += W_s @ vis_s -----------------
// Block b owns slabs [b*SPB, b*SPB+SPB). Per slab: scatter q into W[128c][128v]
// (LDS f32 atomics), stage vis_s^T as swizzled bf16, then 16-wave MFMA
// 128x128 @ 128x180(pad192) accumulating f32 fragments across all 8 slabs.
__global__ __launch_bounds__(GT) void k_mm(
    const uint2* __restrict__ sorted,
    const float* __restrict__ vis,
    const int*   __restrict__ bucketOffs,
    float* __restrict__ out,
    float* __restrict__ partial,
    const int usePartial) {

    __shared__ __align__(16) float    Wf[N_CLUSTERS * 128];   // 65,536 B f32 W accum
    __shared__ __align__(16) unsigned Wb[N_CLUSTERS * 64];    // 32,768 B bf16 W (swizzled)
    __shared__ __align__(16) unsigned Vt[192 * 64];           // 49,152 B bf16 vis^T (swizzled)
    __shared__ int offs[N_CLUSTERS][SPB + 1];                 //  4,608 B

    const int b = blockIdx.x, t = threadIdx.x;
    const int wave = t >> 6, lane = t & 63;
    const int wr = wave >> 2, wc = wave & 3;       // 4x4 wave grid: 32c x 48pmt tiles
    const int s0 = b * SPB;
    const int l15 = lane & 15, lhi = lane >> 4;

    // one-time: zero pad rows 180..191 of Vt (stay zero forever)
    for (int i = t; i < 12 * 64; i += GT) Vt[180 * 64 + i] = 0u;
    // one-time: per-(cluster, slab) segment offsets for this block
    for (int i = t; i < N_CLUSTERS * (SPB + 1); i += GT) {
        const int c = i / (SPB + 1), j = i - c * (SPB + 1);
        offs[c][j] = bucketOffs[(size_t)c * (NBINS + 1) + s0 + j];
    }

    f32x4 acc[2][3];
    #pragma unroll
    for (int mf = 0; mf < 2; ++mf)
        #pragma unroll
        for (int nf = 0; nf < 3; ++nf)
            acc[mf][nf] = (f32x4){0.f, 0.f, 0.f, 0.f};

    const int sc = t >> 3, sj = t & 7;             // scatter: 8 threads per cluster

    for (int s = 0; s < SPB; ++s) {
        // ---- P1: zero Wf ; stage vis slab -> Vt (bf16, transposed, swizzled)
        for (int i = t; i < N_CLUSTERS * 128; i += GT)
            Wf[i] = 0.f;
        {
            const size_t vbase = (size_t)(s0 + s) * 128 * N_PMT;
            #pragma unroll
            for (int r = 0; r < 8; ++r) {
                const int v = wave * 8 + r;                       // slab-local voxel
                const float* srcv = vis + vbase + (size_t)v * N_PMT;
                #pragma unroll
                for (int k3 = 0; k3 < 3; ++k3) {
                    const int p = lane + 64 * k3;
                    if (p < N_PMT) {
                        const unsigned short hv = f2bf(srcv[p]);
                        *((unsigned short*)&Vt[swz_dw(p, v)] + (v & 1)) = hv;
                    }
                }
            }
        }
        __syncthreads();
        // ---- P2: scatter points into Wf (ds_add_f32)
        {
            const int plo = offs[sc][s], phi = offs[sc][s + 1];
            for (int i = plo + sj; i < phi; i += 8) {
                const uint2 e = sorted[i];
                atomicAdd(&Wf[sc * 128 + (int)(e.x & 127u)], __uint_as_float(e.y));
            }
        }
        __syncthreads();
        // ---- P3: convert Wf -> Wb (bf16 pairs, swizzled)
        for (int pid = t; pid < N_CLUSTERS * 64; pid += GT) {
            const int c = pid >> 6, v = (pid & 63) * 2;
            const float f0 = Wf[c * 128 + v], f1 = Wf[c * 128 + v + 1];
            Wb[swz_dw(c, v)] = (unsigned)f2bf(f0) | ((unsigned)f2bf(f1) << 16);
        }
        __syncthreads();
        // ---- P4: MFMA  (A = W[c][k], B = vis^T[p][k] == vis[k][p])
        #pragma unroll
        for (int ks = 0; ks < 4; ++ks) {
            const int kk = ks * 32 + (lhi << 3);   // this lane's k base
            bf16x8 af[2], bf[3];
            #pragma unroll
            for (int mf = 0; mf < 2; ++mf) {
                const int row = wr * 32 + mf * 16 + l15;
                af[mf] = __builtin_bit_cast(bf16x8, *(const uint4*)&Wb[swz_dw(row, kk)]);
            }
            #pragma unroll
            for (int nf = 0; nf < 3; ++nf) {
                const int row = wc * 48 + nf * 16 + l15;
                bf[nf] = __builtin_bit_cast(bf16x8, *(const uint4*)&Vt[swz_dw(row, kk)]);
            }
            #pragma unroll
            for (int mf = 0; mf < 2; ++mf)
                #pragma unroll
                for (int nf = 0; nf < 3; ++nf)
                    acc[mf][nf] = __builtin_amdgcn_mfma_f32_16x16x32_bf16(
                        af[mf], bf[nf], acc[mf][nf], 0, 0, 0);
        }
        __syncthreads();                           // Vt/Wb free for next slab
    }

    // ---- flush: C/D layout col=lane&15 (pmt), row=(lane>>4)*4+i (cluster)
    if (usePartial) {
        float* pdst = partial + (size_t)b * (N_CLUSTERS * N_PMT);
        #pragma unroll
        for (int mf = 0; mf < 2; ++mf)
            #pragma unroll
            for (int nf = 0; nf < 3; ++nf)
                #pragma unroll
                for (int i = 0; i < 4; ++i) {
                    const int c = wr * 32 + mf * 16 + lhi * 4 + i;
                    const int p = wc * 48 + nf * 16 + l15;
                    if (p < N_PMT) pdst[c * N_PMT + p] = acc[mf][nf][i];
                }
    } else {
        #pragma unroll
        for (int mf = 0; mf < 2; ++mf)
            #pragma unroll
            for (int nf = 0; nf < 3; ++nf)
                #pragma unroll
                for (int i = 0; i < 4; ++i) {
                    const int c = wr * 32 + mf * 16 + lhi * 4 + i;
                    const int p = wc * 48 + nf * 16 + l15;
                    if (p < N_PMT) atomicAdd(&out[c * N_PMT + p], acc[mf][nf][i]);
                }
    }
}

__global__ void k_reduce(const float* __restrict__ partial, float* __restrict__ out) {
    const int i = blockIdx.x * 256 + threadIdx.x;
    if (i >= N_CLUSTERS * N_PMT) return;
    float s = 0.f;
    for (int b = 0; b < GBLK; ++b)
        s += partial[(size_t)b * (N_CLUSTERS * N_PMT) + i];
    out[i] = s;
}

// ---------------- fallback (unsorted point-major) ----------------
__global__ void prep_kernel(const float* __restrict__ dx,
                            const int* __restrict__ sizes,
                            const float* __restrict__ dx_ranges,
                            int* __restrict__ offsC,
                            float* __restrict__ dxc) {
    __shared__ int s[N_CLUSTERS];
    const int t = threadIdx.x;      // 128 threads
    s[t] = sizes[t];
    float lo = dx_ranges[2 * t];
    float hi = dx_ranges[2 * t + 1];
    dxc[t] = fminf(fmaxf(dx[t], lo), hi);
    __syncthreads();
    int acc = 0;
    for (int i = 0; i < t; ++i) acc += s[i];
    offsC[t] = acc;
    if (t == N_CLUSTERS - 1) offsC[N_CLUSTERS] = acc + s[t];
}

__global__ __launch_bounds__(BLOCK) void gather_kernel(
    const float4* __restrict__ batch,
    const float4* __restrict__ vis4,
    const int*    __restrict__ offsets,
    const float*  __restrict__ dxc,
    float* __restrict__ out) {
    const int b = blockIdx.x;
    const int c = b / 16, sub = b % 16;
    const int start = offsets[c], end = offsets[c + 1];
    const int count = end - start;
    const int chunk = (count + 15) / 16;
    const int s0 = start + sub * chunk;
    const int s1 = min(s0 + chunk, end);
    const int wave = threadIdx.x >> 6, lane = threadIdx.x & 63;
    const int wtotal = s1 - s0;
    const int per = (wtotal + NWAVE - 1) / NWAVE;
    const int ws0 = s0 + wave * per;
    const int ws1 = min(ws0 + per, s1);
    const float dxc_c = dxc[c];
    const bool active = (lane < 45);
    float4 accE = {0.f, 0.f, 0.f, 0.f};
    for (int base = ws0; base < ws1; base += 64) {
        const int p = base + lane;
        float q = 0.f; int vox = 0;
        if (p < ws1) {
            float4 pd = batch[p];
            int ix = max(0, min(63, (int)floorf(pd.x + dxc_c)));
            int iy = max(0, min(63, (int)floorf(pd.y)));
            int iz = max(0, min(63, (int)floorf(pd.z)));
            vox = ix + 64 * (iy + 64 * iz);
            q = pd.w;
        }
        #pragma unroll
        for (int j = 0; j < 64; ++j) {
            const int   v  = __builtin_amdgcn_readlane(vox, j);
            const float qj = __uint_as_float(__builtin_amdgcn_readlane(__float_as_uint(q), j));
            if (active) {
                float4 r = vis4[(size_t)v * 45 + lane];
                accE.x = fmaf(r.x, qj, accE.x);
                accE.y = fmaf(r.y, qj, accE.y);
                accE.z = fmaf(r.z, qj, accE.z);
                accE.w = fmaf(r.w, qj, accE.w);
            }
        }
    }
    __shared__ float sacc[N_PMT];
    for (int i = threadIdx.x; i < N_PMT; i += BLOCK) sacc[i] = 0.f;
    __syncthreads();
    if (active) {
        atomicAdd(&sacc[lane * 4 + 0], accE.x);
        atomicAdd(&sacc[lane * 4 + 1], accE.y);
        atomicAdd(&sacc[lane * 4 + 2], accE.z);
        atomicAdd(&sacc[lane * 4 + 3], accE.w);
    }
    __syncthreads();
    for (int i = threadIdx.x; i < N_PMT; i += BLOCK)
        atomicAdd(&out[c * N_PMT + i], sacc[i]);
}

extern "C" void kernel_launch(void* const* d_in, const int* in_sizes, int n_in,
                              void* d_out, int out_size, void* d_ws, size_t ws_size,
                              hipStream_t stream) {
    const float* dx        = (const float*)d_in[0];
    const float* batch     = (const float*)d_in[1];
    const int*   sizes     = (const int*)d_in[2];
    const float* dx_ranges = (const float*)d_in[3];
    const float* vis       = (const float*)d_in[4];
    float* out = (float*)d_out;
    char*  wsb = (char*)d_ws;
    const int n = in_sizes[1] / 4;   // total points

    int*   offsC      = (int*)(wsb + 0);
    float* dxc        = (float*)(wsb + 1024);
    int*   bucketOffs = (int*)(wsb + 2048);
    const size_t BO_BYTES   = (size_t)N_CLUSTERS * (NBINS + 1) * 4;          // 1,049,088
    uint2* sorted     = (uint2*)(wsb + 2048 + BO_BYTES);
    const size_t need1      = 2048 + BO_BYTES + 8ull * (size_t)n;
    float* partial    = (float*)(wsb + need1);
    const size_t PART_BYTES = (size_t)GBLK * N_CLUSTERS * N_PMT * 4;         // 23,592,960
    const size_t need2      = need1 + PART_BYTES;

    hipMemsetAsync(out, 0, (size_t)out_size * sizeof(float), stream);

    if (ws_size >= need1) {
        const int usePartial = (ws_size >= need2) ? 1 : 0;
        k_voxsort<<<N_CLUSTERS, SORT_T, 0, stream>>>(
            (const float4*)batch, dx, sizes, dx_ranges, offsC, bucketOffs, sorted);
        k_mm<<<GBLK, GT, 0, stream>>>(
            sorted, vis, bucketOffs, out,
            usePartial ? partial : out, usePartial);
        if (usePartial)
            k_reduce<<<(N_CLUSTERS * N_PMT + 255) / 256, 256, 0, stream>>>(partial, out);
    } else {
        prep_kernel<<<1, N_CLUSTERS, 0, stream>>>(dx, sizes, dx_ranges, offsC, dxc);
        gather_kernel<<<N_CLUSTERS * 16, BLOCK, 0, stream>>>(
            (const float4*)batch, (const float4*)vis, offsC, dxc, out);
    }
}